// Round 20
// baseline (155.692 us; speedup 1.0000x reference)
//
#include <hip/hip_runtime.h>
#include <math.h>

#define BOS_TAG 62
#define EOS_TAG 63
#define S_LEN   1024
#define NCH     16
#define CH      64          // S_LEN / NCH
#define WPB     1           // NCH/16 fwd waves per batch (same for bwd)
#define LN2F    0.69314718055994530942f

typedef short  short8 __attribute__((ext_vector_type(8)));
typedef float  f32x4  __attribute__((ext_vector_type(4)));

template <int CTRL>
__device__ __forceinline__ int dpp_mov(int v) {
  return __builtin_amdgcn_update_dpp(v, v, CTRL, 0xf, 0xf, false);
}
template <int CTRL>
__device__ __forceinline__ float dpp_fmax_step(float v) {
  return fmaxf(v, __int_as_float(dpp_mov<CTRL>(__float_as_int(v))));
}
__device__ __forceinline__ float wave_fmax_all(float v) {
  v = dpp_fmax_step<0x111>(v); v = dpp_fmax_step<0x112>(v);
  v = dpp_fmax_step<0x114>(v); v = dpp_fmax_step<0x118>(v);
  v = dpp_fmax_step<0x142>(v); v = dpp_fmax_step<0x143>(v);
  return __int_as_float(__builtin_amdgcn_readlane(__float_as_int(v), 63));
}
template <int CTRL>
__device__ __forceinline__ float dpp_fadd_step(float v) {
  int t = __builtin_amdgcn_update_dpp(0, __float_as_int(v), CTRL, 0xf, 0xf, true);
  return v + __int_as_float(t);
}
__device__ __forceinline__ float wave_sum_all(float v) {
  v = dpp_fadd_step<0x111>(v); v = dpp_fadd_step<0x112>(v);
  v = dpp_fadd_step<0x114>(v); v = dpp_fadd_step<0x118>(v);
  v = dpp_fadd_step<0x142>(v); v = dpp_fadd_step<0x143>(v);
  return __int_as_float(__builtin_amdgcn_readlane(__float_as_int(v), 63));
}
__device__ __forceinline__ unsigned short f2bf(float v) {   // round-half-up (positive)
  return (unsigned short)((__float_as_uint(v) + 0x8000u) >> 16);
}
__device__ __forceinline__ float bf2f(unsigned short u) {
  return __uint_as_float(((unsigned)u) << 16);
}

// ===== prep: lens for all batches; block 0 also builds pfrag/tvf + zeroes out =====
// ptab layout: entry e = ((dir*4 + m)*2 + kc)*64 + lane. lane=(g,c);
//   out-state = 16*m + c ; in-state = 16*(2*kc + (j>>2)) + 4*g + (j&3)
//   fwd (v' = P^T v): A[out][in] = exp(trans[in*64+out]); bwd: exp(trans[out*64+in])
__global__ __launch_bounds__(256) void crf_prep(
    const float* __restrict__ mask, const float* __restrict__ trans,
    int* __restrict__ lens, short8* __restrict__ pfrag,
    float* __restrict__ tvf, float* __restrict__ out, int B)
{
  const int tid = threadIdx.x;
  const int b = blockIdx.x * 4 + (tid >> 6);
  if (b < B) {
    const int l = tid & 63;
    const float4* mb = (const float4*)(mask + (size_t)b * S_LEN);
    float s = 0.f;
#pragma unroll
    for (int i = 0; i < 4; ++i) { float4 q = mb[l + 64 * i]; s += q.x + q.y + q.z + q.w; }
    s = wave_sum_all(s);
    if (l == 0) lens[b] = max(1, min(S_LEN, (int)(s + 0.5f)));
  }
  if (blockIdx.x == 0) {
    for (int e = tid; e < 1024; e += 256) {
      int lane = e & 63, kc = (e >> 6) & 1, m = (e >> 7) & 3, dir = e >> 9;
      int g = lane >> 4, c = lane & 15;
      int out_s = 16 * m + c;
      short8 f;
#pragma unroll
      for (int j = 0; j < 8; ++j) {
        int in_s = 16 * (2 * kc + (j >> 2)) + 4 * g + (j & 3);
        float tv = dir ? trans[out_s * 64 + in_s] : trans[in_s * 64 + out_s];
        f[j] = (short)f2bf(__expf(tv));
      }
      pfrag[e] = f;
    }
    if (tid < 64) tvf[tid] = __expf(trans[tid * 64 + EOS_TAG]);
    if (tid == 0) out[0] = 0.f;
  }
}

// ===== register-resident MFMA chunk kernel (no LDS; CH=64 geometry) =====
// wave w: dir=w&1, b=w>>1 (WPB==1, half==0). Chain r <-> chunk kg=r lives in
// COLUMN r. Per-lane state d[m][reg] = V[state 16m+4g+reg][chain c], f32.
// Step: pack d -> bf16 B-frags (lane-local by ptab's sigma permutation),
// acc[m] = A[m][0]xB0 + A[m][1]xB1, fwd: d = acc .* exp(E); bwd: pack
// includes .*exp(E), d = acc. Renorm every 4 steps. Saves: chain r by c==r.
// NOTES: NEVER runtime-index per-thread arrays (R12-R15 scratch saga).
__global__ __launch_bounds__(256, 2) void crf_chunk_mfma(
    const float* __restrict__ em, const float* __restrict__ trans,
    const int* __restrict__ lens, const short8* __restrict__ pfrag,
    unsigned short* __restrict__ Vf, unsigned short* __restrict__ Vb,
    float* __restrict__ sf, float* __restrict__ sb,
    float* __restrict__ m0a, int B)
{
  const int l  = threadIdx.x & 63;
  const int w  = blockIdx.x * 4 + (threadIdx.x >> 6);
  const int nwaves = 2 * B * WPB;
  if (w >= nwaves) return;
  const int dir  = w & 1;
  const int b    = w >> 1;
  const int half = 0;
  const float* embase = em + (size_t)b * S_LEN * 64;
  const int g = l >> 4, c = l & 15;

  const int len = lens[b];

  // ---- m0 (fwd only) ----
  float m0 = 0.f;
  if (dir == 0) {
    float a0 = trans[BOS_TAG * 64 + l] + embase[l];
    m0 = wave_fmax_all(a0);
    if (l == 0) m0a[b] = m0;
  }

  // ---- pre-save empty chunks; find the partial chunk (scalars only) ----
  unsigned short* Vout = dir ? Vb : Vf;
  float* sout = dir ? sb : sf;
  int ps = -1, pr = -1;
#pragma unroll
  for (int r = 0; r < 16; ++r) {
    int kg = half * 16 + r;
    int fs = min((kg + 1) * CH, len - 1) - (kg * CH + 1);
    if (fs < 0) {
      Vout[((size_t)b * NCH + kg) * 64 + l] = 0x3F80; // bf16 1.0
      if (l == 0) sout[b * NCH + kg] = 0.f;
    }
    if (fs >= 0 && fs < CH - 1) { ps = fs; pr = r; }
  }

  // (half==0, len>=1 -> never fully empty; skip the empty-wave exit)

  // ---- A fragments (static P), 8 coalesced 16B loads ----
  short8 Af[4][2];
#pragma unroll
  for (int m = 0; m < 4; ++m)
#pragma unroll
    for (int kc = 0; kc < 2; ++kc)
      Af[m][kc] = pfrag[((dir * 4 + m) * 2 + kc) * 64 + l];

  // ---- init d: fwd chain 0 = exp(alpha0 - m0), else 1.0 ----
  float d[4][4];
#pragma unroll
  for (int m = 0; m < 4; ++m)
#pragma unroll
    for (int r = 0; r < 4; ++r) d[m][r] = 1.0f;
  if (dir == 0 && c == 0) {
#pragma unroll
    for (int m = 0; m < 4; ++m) {
      float4 tq = *reinterpret_cast<const float4*>(trans + BOS_TAG * 64 + 16 * m + 4 * g);
      float4 eq = *reinterpret_cast<const float4*>(embase + 16 * m + 4 * g);
      d[m][0] = __expf(tq.x + eq.x - m0);
      d[m][1] = __expf(tq.y + eq.y - m0);
      d[m][2] = __expf(tq.z + eq.z - m0);
      d[m][3] = __expf(tq.w + eq.w - m0);
    }
  }

  int sigma = 0;
  auto renorm16 = [&]() {
    float mx = d[0][0];
#pragma unroll
    for (int m = 0; m < 4; ++m)
#pragma unroll
      for (int r = 0; r < 4; ++r) mx = fmaxf(mx, d[m][r]);
    mx = wave_fmax_all(mx);
    int e = ((__float_as_int(mx) >> 23) & 0xff) - 127;
    float s = __int_as_float((127 - e) << 23);
#pragma unroll
    for (int m = 0; m < 4; ++m)
#pragma unroll
      for (int r = 0; r < 4; ++r) d[m][r] *= s;
    sigma += e;
  };
  auto save_chain = [&](int r) {
    int kg = half * 16 + r;
    if (c == r) {
      unsigned short* dst = Vout + ((size_t)b * NCH + kg) * 64;
#pragma unroll
      for (int m = 0; m < 4; ++m) {
        uint2 val;
        val.x = (unsigned)f2bf(d[m][0]) | ((unsigned)f2bf(d[m][1]) << 16);
        val.y = (unsigned)f2bf(d[m][2]) | ((unsigned)f2bf(d[m][3]) << 16);
        *reinterpret_cast<uint2*>(dst + 16 * m + 4 * g) = val;
      }
    }
    if (l == r) sout[b * NCH + kg] = (float)sigma;
  };

  // ---- emission addressing: one row t_c per lane, 4 x float4 ----
  const int tb0c  = (half * 16 + c) * CH + 1;
  const int tendc = min((half * 16 + c + 1) * CH, len - 1);
  auto loadE = [&](float4* q, int tl) {
    int tr = dir ? max(tendc - tl, 0) : min(tb0c + tl, S_LEN - 1);
    const float* rowp = embase + (size_t)tr * 64 + 4 * g;
    q[0] = *reinterpret_cast<const float4*>(rowp);
    q[1] = *reinterpret_cast<const float4*>(rowp + 16);
    q[2] = *reinterpret_cast<const float4*>(rowp + 32);
    q[3] = *reinterpret_cast<const float4*>(rowp + 48);
  };

  auto mfma8 = [&](const short8& bv0, const short8& bv1, f32x4* acc) {
#pragma unroll
    for (int m = 0; m < 4; ++m) {
      f32x4 z = {0.f, 0.f, 0.f, 0.f};
      z = __builtin_amdgcn_mfma_f32_16x16x32_bf16(Af[m][0], bv0, z, 0, 0, 0);
      acc[m] = __builtin_amdgcn_mfma_f32_16x16x32_bf16(Af[m][1], bv1, z, 0, 0, 0);
    }
  };

  auto bodyF = [&](const float4* q, int tl, bool rn) {
    short8 bv0, bv1;
#pragma unroll
    for (int j = 0; j < 8; ++j) {
      bv0[j] = (short)f2bf(d[(j >> 2)][j & 3]);
      bv1[j] = (short)f2bf(d[2 + (j >> 2)][j & 3]);
    }
    f32x4 acc[4];
    mfma8(bv0, bv1, acc);
#pragma unroll
    for (int m = 0; m < 4; ++m) {
      d[m][0] = acc[m][0] * __expf(q[m].x);
      d[m][1] = acc[m][1] * __expf(q[m].y);
      d[m][2] = acc[m][2] * __expf(q[m].z);
      d[m][3] = acc[m][3] * __expf(q[m].w);
    }
    if (rn) renorm16();
    if (tl == ps) save_chain(pr);
  };
  auto bodyB = [&](const float4* q, int tl, bool rn) {
    float ex[4][4];
#pragma unroll
    for (int m = 0; m < 4; ++m) {
      ex[m][0] = __expf(q[m].x); ex[m][1] = __expf(q[m].y);
      ex[m][2] = __expf(q[m].z); ex[m][3] = __expf(q[m].w);
    }
    short8 bv0, bv1;
#pragma unroll
    for (int j = 0; j < 8; ++j) {
      bv0[j] = (short)f2bf(d[(j >> 2)][j & 3] * ex[(j >> 2)][j & 3]);
      bv1[j] = (short)f2bf(d[2 + (j >> 2)][j & 3] * ex[2 + (j >> 2)][j & 3]);
    }
    f32x4 acc[4];
    mfma8(bv0, bv1, acc);
#pragma unroll
    for (int m = 0; m < 4; ++m) {
      d[m][0] = acc[m][0]; d[m][1] = acc[m][1];
      d[m][2] = acc[m][2]; d[m][3] = acc[m][3];
    }
    if (rn) renorm16();
    if (tl == ps) save_chain(pr);
  };

  // ---- main loop: depth-4 E prefetch, 4-step unroll ----
  float4 p0[4], p1[4], p2[4], p3[4];
  loadE(p0, 0); loadE(p1, 1); loadE(p2, 2); loadE(p3, 3);
  if (dir == 0) {
#pragma unroll 1
    for (int t4 = 0; t4 < CH; t4 += 4) {
      bodyF(p0, t4 + 0, false); loadE(p0, t4 + 4);
      bodyF(p1, t4 + 1, false); loadE(p1, t4 + 5);
      bodyF(p2, t4 + 2, false); loadE(p2, t4 + 6);
      bodyF(p3, t4 + 3, true);  loadE(p3, t4 + 7);
    }
  } else {
#pragma unroll 1
    for (int t4 = 0; t4 < CH; t4 += 4) {
      bodyB(p0, t4 + 0, false); loadE(p0, t4 + 4);
      bodyB(p1, t4 + 1, false); loadE(p1, t4 + 5);
      bodyB(p2, t4 + 2, false); loadE(p2, t4 + 6);
      bodyB(p3, t4 + 3, true);  loadE(p3, t4 + 7);
    }
  }

  // ---- final saves: every lane saves its own chain c if full ----
  {
    int kg = half * 16 + c;
    bool full = (kg + 1) * CH <= len - 1;
    if (full) {
      unsigned short* dst = Vout + ((size_t)b * NCH + kg) * 64;
#pragma unroll
      for (int m = 0; m < 4; ++m) {
        uint2 val;
        val.x = (unsigned)f2bf(d[m][0]) | ((unsigned)f2bf(d[m][1]) << 16);
        val.y = (unsigned)f2bf(d[m][2]) | ((unsigned)f2bf(d[m][3]) << 16);
        *reinterpret_cast<uint2*>(dst + 16 * m + 4 * g) = val;
      }
    }
    if (l < 16 && (half * 16 + l + 1) * CH <= len - 1)
      sout[b * NCH + half * 16 + l] = (float)sigma;
  }
}

// ===== combine: one wave per (b,k) term; atomicAdd to out (no final kernel) =====
__global__ __launch_bounds__(256) void crf_combine(
    const float* __restrict__ em, const int* __restrict__ tags,
    const float* __restrict__ trans, const int* __restrict__ lens,
    const unsigned short* __restrict__ Vf, const unsigned short* __restrict__ Vb,
    const float* __restrict__ sf, const float* __restrict__ sb,
    const float* __restrict__ m0a, const float* __restrict__ tvf,
    float* __restrict__ out, int B)
{
  const int item = blockIdx.x * 4 + (threadIdx.x >> 6);
  if (item >= B * NCH) return;
  const int b = item / NCH, k = item - b * NCH;
  const int l = threadIdx.x & 63;
  const int len = lens[b];
  const int kb = (len >= 2) ? (len - 2) / CH : 0;

  const int* tb = tags + (size_t)b * S_LEN;
  const float* emb = em + (size_t)b * S_LEN * 64;

  float t = 0.f;
  // ---- gold score slice (negated): steps t0 = k*CH+1 .. min((k+1)CH, len-1)
  {
    float sc = 0.f;
    int t0 = k * CH + 1 + l;
    if (t0 <= min((k + 1) * CH, len - 1)) {
      int cur = tb[t0], prev = tb[t0 - 1];
      sc = emb[(size_t)t0 * 64 + cur] + trans[prev * 64 + cur];
    }
    if (k == 0) {
      if (l == 32 || (l == 33)) {
        // lane 32: start terms; lane 33: end term (wave_sum merges)
        sc += (l == 32) ? (trans[BOS_TAG * 64 + tb[0]] + emb[tb[0]])
                        : trans[tb[len - 1] * 64 + EOS_TAG];
      }
    }
    t -= wave_sum_all(sc);
  }

  const unsigned short* vf = Vf + ((size_t)b * NCH + k) * 64;
  if (k == 0) {
    float v0 = bf2f(vf[l]);
    if (kb == 0) {
      t += m0a[b] + LN2F * sf[b * NCH] + __logf(wave_sum_all(v0 * tvf[l]));
    } else {
      t += m0a[b] + LN2F * (sf[b * NCH] + sb[b * NCH + 1])
         + __logf(wave_sum_all(v0 * bf2f(Vb[((size_t)b * NCH + 1) * 64 + l])));
    }
  } else if (k < kb) {
    float vk = bf2f(vf[l]);
    t += LN2F * sb[b * NCH + k + 1]
       + __logf(wave_sum_all(vk * bf2f(Vb[((size_t)b * NCH + k + 1) * 64 + l])))
       - __logf(wave_sum_all(vk));
  } else if (k == kb) {
    float vk = bf2f(vf[l]);
    t += __logf(wave_sum_all(vk * tvf[l])) - __logf(wave_sum_all(vk));
  }

  if (l == 0) atomicAdd(out, t);
}

// ===== fallback: monolithic per-batch forward (VALU, linear space) =====
__global__ __launch_bounds__(64) void crf_mono(
    const float* __restrict__ em, const int* __restrict__ tags,
    const float* __restrict__ mask, const float* __restrict__ trans,
    float* __restrict__ partial)
{
  const int b = blockIdx.x;
  const int l = threadIdx.x;
  const float* emb = em + (size_t)b * S_LEN * 64;
  const float* mb = mask + (size_t)b * S_LEN;
  float lenf = 0.f;
  for (int t = l; t < S_LEN; t += 64) lenf += mb[t];
  lenf = wave_sum_all(lenf);
  const int len = max(1, min(S_LEN, (int)(lenf + 0.5f)));

  float p[64];
#pragma unroll
  for (int i = 0; i < 64; ++i) p[i] = __expf(trans[i * 64 + l]) * 0.015625f;

  const int* tb = tags + (size_t)b * S_LEN;
  float sc = 0.f;
  for (int tt = 1 + l; tt <= len - 1; tt += 64)
    sc += emb[(size_t)tt * 64 + tb[tt]] + trans[tb[tt - 1] * 64 + tb[tt]];
  sc = wave_sum_all(sc);
  sc += trans[BOS_TAG * 64 + tb[0]] + emb[tb[0]] + trans[tb[len - 1] * 64 + EOS_TAG];

  float a0 = trans[BOS_TAG * 64 + l] + emb[l];
  float m0 = wave_fmax_all(a0);
  float v = __expf(a0 - m0);
  int sigma = 0;
  for (int t = 1; t <= len - 1; ++t) {
    float E = __expf(emb[(size_t)t * 64 + l]);
    int xi = __float_as_int(v);
    float s0 = 0.f, s1 = 0.f, s2 = 0.f, s3 = 0.f;
#pragma unroll
    for (int i = 0; i < 64; i += 4) {
      s0 = fmaf(__int_as_float(__builtin_amdgcn_readlane(xi, i + 0)), p[i + 0], s0);
      s1 = fmaf(__int_as_float(__builtin_amdgcn_readlane(xi, i + 1)), p[i + 1], s1);
      s2 = fmaf(__int_as_float(__builtin_amdgcn_readlane(xi, i + 2)), p[i + 2], s2);
      s3 = fmaf(__int_as_float(__builtin_amdgcn_readlane(xi, i + 3)), p[i + 3], s3);
    }
    v = ((s0 + s1) + (s2 + s3)) * E;
    float m = wave_fmax_all(v);
    int e = ((__float_as_int(m) >> 23) & 0xff) - 127;
    sigma += e + 6;
    v *= __int_as_float((127 - e) << 23);
  }
  float tvec = __expf(trans[l * 64 + EOS_TAG]);
  float lp = m0 + LN2F * (float)sigma + __logf(wave_sum_all(v * tvec));
  if (l == 0) partial[b] = lp - sc;
}

__global__ __launch_bounds__(1024) void crf_final(
    const float* __restrict__ term, float* __restrict__ out, int n)
{
  __shared__ float red[16];
  float s = 0.f;
  for (int i = threadIdx.x; i < n; i += 1024) s += term[i];
  s = wave_sum_all(s);
  const int wid = threadIdx.x >> 6;
  if ((threadIdx.x & 63) == 0) red[wid] = s;
  __syncthreads();
  if (threadIdx.x == 0) {
    float tot = 0.f;
#pragma unroll
    for (int i = 0; i < 16; ++i) tot += red[i];
    out[0] = tot;
  }
}

extern "C" void kernel_launch(void* const* d_in, const int* in_sizes, int n_in,
                              void* d_out, int out_size, void* d_ws, size_t ws_size,
                              hipStream_t stream) {
  const float* em = (const float*)d_in[0];
  const int* tags = (const int*)d_in[1];
  const float* mask = (const float*)d_in[2];
  const float* trans = (const float*)d_in[3];
  float* out = (float*)d_out;

  const int B = in_sizes[1] / S_LEN;

  const size_t nSig = (size_t)B * NCH;
  const size_t nV   = (size_t)B * NCH * 64;
  const size_t need = 16384 + 64 * sizeof(float)
                    + (2 * nSig + (size_t)B) * sizeof(float)
                    + (size_t)B * sizeof(int)
                    + 2 * nV * sizeof(unsigned short);

  if (ws_size >= need) {
    short8* pfrag = (short8*)d_ws;
    float* tvf  = (float*)((char*)d_ws + 16384);
    float* sf   = tvf + 64;
    float* sb   = sf + nSig;
    float* m0a  = sb + nSig;
    int*   lens = (int*)(m0a + B);
    unsigned short* Vf = (unsigned short*)(lens + B);
    unsigned short* Vb = Vf + nV;

    crf_prep<<<(B + 3) / 4, 256, 0, stream>>>(mask, trans, lens, pfrag, tvf, out, B);
    const int nwaves = 2 * B * WPB;
    crf_chunk_mfma<<<(nwaves + 3) / 4, 256, 0, stream>>>(
        em, trans, lens, pfrag, Vf, Vb, sf, sb, m0a, B);
    crf_combine<<<(B * NCH + 3) / 4, 256, 0, stream>>>(
        em, tags, trans, lens, Vf, Vb, sf, sb, m0a, tvf, out, B);
  } else {
    float* partial = (float*)d_ws;
    crf_mono<<<B, 64, 0, stream>>>(em, tags, mask, trans, partial);
    crf_final<<<1, 1024, 0, stream>>>(partial, out, B);
  }
}

// Round 21
// 62.045 us; speedup vs baseline: 2.5093x; 2.5093x over previous
//
#include <hip/hip_runtime.h>
#include <math.h>

#define BOS_TAG 62
#define EOS_TAG 63
#define S_LEN   1024
#define NCH     16
#define CH      64          // S_LEN / NCH
#define WPB     1           // NCH/16 fwd waves per batch (same for bwd)
#define LN2F    0.69314718055994530942f

typedef short  short8 __attribute__((ext_vector_type(8)));
typedef float  f32x4  __attribute__((ext_vector_type(4)));

template <int CTRL>
__device__ __forceinline__ int dpp_mov(int v) {
  return __builtin_amdgcn_update_dpp(v, v, CTRL, 0xf, 0xf, false);
}
template <int CTRL>
__device__ __forceinline__ float dpp_fmax_step(float v) {
  return fmaxf(v, __int_as_float(dpp_mov<CTRL>(__float_as_int(v))));
}
__device__ __forceinline__ float wave_fmax_all(float v) {
  v = dpp_fmax_step<0x111>(v); v = dpp_fmax_step<0x112>(v);
  v = dpp_fmax_step<0x114>(v); v = dpp_fmax_step<0x118>(v);
  v = dpp_fmax_step<0x142>(v); v = dpp_fmax_step<0x143>(v);
  return __int_as_float(__builtin_amdgcn_readlane(__float_as_int(v), 63));
}
template <int CTRL>
__device__ __forceinline__ float dpp_fadd_step(float v) {
  int t = __builtin_amdgcn_update_dpp(0, __float_as_int(v), CTRL, 0xf, 0xf, true);
  return v + __int_as_float(t);
}
__device__ __forceinline__ float wave_sum_all(float v) {
  v = dpp_fadd_step<0x111>(v); v = dpp_fadd_step<0x112>(v);
  v = dpp_fadd_step<0x114>(v); v = dpp_fadd_step<0x118>(v);
  v = dpp_fadd_step<0x142>(v); v = dpp_fadd_step<0x143>(v);
  return __int_as_float(__builtin_amdgcn_readlane(__float_as_int(v), 63));
}
__device__ __forceinline__ unsigned short f2bf(float v) {   // round-half-up (positive)
  return (unsigned short)((__float_as_uint(v) + 0x8000u) >> 16);
}
__device__ __forceinline__ float bf2f(unsigned short u) {
  return __uint_as_float(((unsigned)u) << 16);
}

// ===== prep: lens for all batches; block 0 also builds pfrag/tvf =====
// ptab layout: entry e = ((dir*4 + m)*2 + kc)*64 + lane. lane=(g,c);
//   out-state = 16*m + c ; in-state = 16*(2*kc + (j>>2)) + 4*g + (j&3)
//   fwd (v' = P^T v): A[out][in] = exp(trans[in*64+out]); bwd: exp(trans[out*64+in])
__global__ __launch_bounds__(256) void crf_prep(
    const float* __restrict__ mask, const float* __restrict__ trans,
    int* __restrict__ lens, short8* __restrict__ pfrag,
    float* __restrict__ tvf, int B)
{
  const int tid = threadIdx.x;
  const int b = blockIdx.x * 4 + (tid >> 6);
  if (b < B) {
    const int l = tid & 63;
    const float4* mb = (const float4*)(mask + (size_t)b * S_LEN);
    float s = 0.f;
#pragma unroll
    for (int i = 0; i < 4; ++i) { float4 q = mb[l + 64 * i]; s += q.x + q.y + q.z + q.w; }
    s = wave_sum_all(s);
    if (l == 0) lens[b] = max(1, min(S_LEN, (int)(s + 0.5f)));
  }
  if (blockIdx.x == 0) {
    for (int e = tid; e < 1024; e += 256) {
      int lane = e & 63, kc = (e >> 6) & 1, m = (e >> 7) & 3, dir = e >> 9;
      int g = lane >> 4, c = lane & 15;
      int out_s = 16 * m + c;
      short8 f;
#pragma unroll
      for (int j = 0; j < 8; ++j) {
        int in_s = 16 * (2 * kc + (j >> 2)) + 4 * g + (j & 3);
        float tv = dir ? trans[out_s * 64 + in_s] : trans[in_s * 64 + out_s];
        f[j] = (short)f2bf(__expf(tv));
      }
      pfrag[e] = f;
    }
    if (tid < 64) tvf[tid] = __expf(trans[tid * 64 + EOS_TAG]);
  }
}

// ===== register-resident MFMA chunk kernel (no LDS; CH=64 geometry) =====
// wave w: dir=w&1, b=w>>1 (WPB==1, half==0). Chain r <-> chunk kg=r lives in
// COLUMN r. Per-lane state d[m][reg] = V[state 16m+4g+reg][chain c], f32.
// Step: pack d -> bf16 B-frags (lane-local by ptab's sigma permutation),
// acc[m] = A[m][0]xB0 + A[m][1]xB1, fwd: d = acc .* exp(E); bwd: pack
// includes .*exp(E), d = acc. Renorm every 4 steps. Saves: chain r by c==r.
// NOTES: NEVER runtime-index per-thread arrays (R12-R15 scratch saga).
// NEVER single-address atomicAdd reduction (R20: 8192 atomics = 107us).
__global__ __launch_bounds__(256, 2) void crf_chunk_mfma(
    const float* __restrict__ em, const float* __restrict__ trans,
    const int* __restrict__ lens, const short8* __restrict__ pfrag,
    unsigned short* __restrict__ Vf, unsigned short* __restrict__ Vb,
    float* __restrict__ sf, float* __restrict__ sb,
    float* __restrict__ m0a, int B)
{
  const int l  = threadIdx.x & 63;
  const int w  = blockIdx.x * 4 + (threadIdx.x >> 6);
  const int nwaves = 2 * B * WPB;
  if (w >= nwaves) return;
  const int dir  = w & 1;
  const int b    = w >> 1;
  const int half = 0;
  const float* embase = em + (size_t)b * S_LEN * 64;
  const int g = l >> 4, c = l & 15;

  const int len = lens[b];

  // ---- m0 (fwd only) ----
  float m0 = 0.f;
  if (dir == 0) {
    float a0 = trans[BOS_TAG * 64 + l] + embase[l];
    m0 = wave_fmax_all(a0);
    if (l == 0) m0a[b] = m0;
  }

  // ---- pre-save empty chunks; find the partial chunk (scalars only) ----
  unsigned short* Vout = dir ? Vb : Vf;
  float* sout = dir ? sb : sf;
  int ps = -1, pr = -1;
#pragma unroll
  for (int r = 0; r < 16; ++r) {
    int kg = half * 16 + r;
    int fs = min((kg + 1) * CH, len - 1) - (kg * CH + 1);
    if (fs < 0) {
      Vout[((size_t)b * NCH + kg) * 64 + l] = 0x3F80; // bf16 1.0
      if (l == 0) sout[b * NCH + kg] = 0.f;
    }
    if (fs >= 0 && fs < CH - 1) { ps = fs; pr = r; }
  }

  // ---- A fragments (static P), 8 coalesced 16B loads ----
  short8 Af[4][2];
#pragma unroll
  for (int m = 0; m < 4; ++m)
#pragma unroll
    for (int kc = 0; kc < 2; ++kc)
      Af[m][kc] = pfrag[((dir * 4 + m) * 2 + kc) * 64 + l];

  // ---- init d: fwd chain 0 = exp(alpha0 - m0), else 1.0 ----
  float d[4][4];
#pragma unroll
  for (int m = 0; m < 4; ++m)
#pragma unroll
    for (int r = 0; r < 4; ++r) d[m][r] = 1.0f;
  if (dir == 0 && c == 0) {
#pragma unroll
    for (int m = 0; m < 4; ++m) {
      float4 tq = *reinterpret_cast<const float4*>(trans + BOS_TAG * 64 + 16 * m + 4 * g);
      float4 eq = *reinterpret_cast<const float4*>(embase + 16 * m + 4 * g);
      d[m][0] = __expf(tq.x + eq.x - m0);
      d[m][1] = __expf(tq.y + eq.y - m0);
      d[m][2] = __expf(tq.z + eq.z - m0);
      d[m][3] = __expf(tq.w + eq.w - m0);
    }
  }

  int sigma = 0;
  auto renorm16 = [&]() {
    float mx = d[0][0];
#pragma unroll
    for (int m = 0; m < 4; ++m)
#pragma unroll
      for (int r = 0; r < 4; ++r) mx = fmaxf(mx, d[m][r]);
    mx = wave_fmax_all(mx);
    int e = ((__float_as_int(mx) >> 23) & 0xff) - 127;
    float s = __int_as_float((127 - e) << 23);
#pragma unroll
    for (int m = 0; m < 4; ++m)
#pragma unroll
      for (int r = 0; r < 4; ++r) d[m][r] *= s;
    sigma += e;
  };
  auto save_chain = [&](int r) {
    int kg = half * 16 + r;
    if (c == r) {
      unsigned short* dst = Vout + ((size_t)b * NCH + kg) * 64;
#pragma unroll
      for (int m = 0; m < 4; ++m) {
        uint2 val;
        val.x = (unsigned)f2bf(d[m][0]) | ((unsigned)f2bf(d[m][1]) << 16);
        val.y = (unsigned)f2bf(d[m][2]) | ((unsigned)f2bf(d[m][3]) << 16);
        *reinterpret_cast<uint2*>(dst + 16 * m + 4 * g) = val;
      }
    }
    if (l == r) sout[b * NCH + kg] = (float)sigma;
  };

  // ---- emission addressing: one row t_c per lane, 4 x float4 ----
  const int tb0c  = (half * 16 + c) * CH + 1;
  const int tendc = min((half * 16 + c + 1) * CH, len - 1);
  auto loadE = [&](float4* q, int tl) {
    int tr = dir ? max(tendc - tl, 0) : min(tb0c + tl, S_LEN - 1);
    const float* rowp = embase + (size_t)tr * 64 + 4 * g;
    q[0] = *reinterpret_cast<const float4*>(rowp);
    q[1] = *reinterpret_cast<const float4*>(rowp + 16);
    q[2] = *reinterpret_cast<const float4*>(rowp + 32);
    q[3] = *reinterpret_cast<const float4*>(rowp + 48);
  };

  auto mfma8 = [&](const short8& bv0, const short8& bv1, f32x4* acc) {
#pragma unroll
    for (int m = 0; m < 4; ++m) {
      f32x4 z = {0.f, 0.f, 0.f, 0.f};
      z = __builtin_amdgcn_mfma_f32_16x16x32_bf16(Af[m][0], bv0, z, 0, 0, 0);
      acc[m] = __builtin_amdgcn_mfma_f32_16x16x32_bf16(Af[m][1], bv1, z, 0, 0, 0);
    }
  };

  auto bodyF = [&](const float4* q, int tl, bool rn) {
    short8 bv0, bv1;
#pragma unroll
    for (int j = 0; j < 8; ++j) {
      bv0[j] = (short)f2bf(d[(j >> 2)][j & 3]);
      bv1[j] = (short)f2bf(d[2 + (j >> 2)][j & 3]);
    }
    f32x4 acc[4];
    mfma8(bv0, bv1, acc);
#pragma unroll
    for (int m = 0; m < 4; ++m) {
      d[m][0] = acc[m][0] * __expf(q[m].x);
      d[m][1] = acc[m][1] * __expf(q[m].y);
      d[m][2] = acc[m][2] * __expf(q[m].z);
      d[m][3] = acc[m][3] * __expf(q[m].w);
    }
    if (rn) renorm16();
    if (tl == ps) save_chain(pr);
  };
  auto bodyB = [&](const float4* q, int tl, bool rn) {
    float ex[4][4];
#pragma unroll
    for (int m = 0; m < 4; ++m) {
      ex[m][0] = __expf(q[m].x); ex[m][1] = __expf(q[m].y);
      ex[m][2] = __expf(q[m].z); ex[m][3] = __expf(q[m].w);
    }
    short8 bv0, bv1;
#pragma unroll
    for (int j = 0; j < 8; ++j) {
      bv0[j] = (short)f2bf(d[(j >> 2)][j & 3] * ex[(j >> 2)][j & 3]);
      bv1[j] = (short)f2bf(d[2 + (j >> 2)][j & 3] * ex[2 + (j >> 2)][j & 3]);
    }
    f32x4 acc[4];
    mfma8(bv0, bv1, acc);
#pragma unroll
    for (int m = 0; m < 4; ++m) {
      d[m][0] = acc[m][0]; d[m][1] = acc[m][1];
      d[m][2] = acc[m][2]; d[m][3] = acc[m][3];
    }
    if (rn) renorm16();
    if (tl == ps) save_chain(pr);
  };

  // ---- main loop: depth-4 E prefetch, 4-step unroll ----
  float4 p0[4], p1[4], p2[4], p3[4];
  loadE(p0, 0); loadE(p1, 1); loadE(p2, 2); loadE(p3, 3);
  if (dir == 0) {
#pragma unroll 1
    for (int t4 = 0; t4 < CH; t4 += 4) {
      bodyF(p0, t4 + 0, false); loadE(p0, t4 + 4);
      bodyF(p1, t4 + 1, false); loadE(p1, t4 + 5);
      bodyF(p2, t4 + 2, false); loadE(p2, t4 + 6);
      bodyF(p3, t4 + 3, true);  loadE(p3, t4 + 7);
    }
  } else {
#pragma unroll 1
    for (int t4 = 0; t4 < CH; t4 += 4) {
      bodyB(p0, t4 + 0, false); loadE(p0, t4 + 4);
      bodyB(p1, t4 + 1, false); loadE(p1, t4 + 5);
      bodyB(p2, t4 + 2, false); loadE(p2, t4 + 6);
      bodyB(p3, t4 + 3, true);  loadE(p3, t4 + 7);
    }
  }

  // ---- final saves: every lane saves its own chain c if full ----
  {
    int kg = half * 16 + c;
    bool full = (kg + 1) * CH <= len - 1;
    if (full) {
      unsigned short* dst = Vout + ((size_t)b * NCH + kg) * 64;
#pragma unroll
      for (int m = 0; m < 4; ++m) {
        uint2 val;
        val.x = (unsigned)f2bf(d[m][0]) | ((unsigned)f2bf(d[m][1]) << 16);
        val.y = (unsigned)f2bf(d[m][2]) | ((unsigned)f2bf(d[m][3]) << 16);
        *reinterpret_cast<uint2*>(dst + 16 * m + 4 * g) = val;
      }
    }
    if (l < 16 && (half * 16 + l + 1) * CH <= len - 1)
      sout[b * NCH + half * 16 + l] = (float)sigma;
  }
}

// ===== combine: one wave per (b,k) term -> term[item] =====
__global__ __launch_bounds__(256) void crf_combine(
    const float* __restrict__ em, const int* __restrict__ tags,
    const float* __restrict__ trans, const int* __restrict__ lens,
    const unsigned short* __restrict__ Vf, const unsigned short* __restrict__ Vb,
    const float* __restrict__ sf, const float* __restrict__ sb,
    const float* __restrict__ m0a, const float* __restrict__ tvf,
    float* __restrict__ term, int B)
{
  const int item = blockIdx.x * 4 + (threadIdx.x >> 6);
  if (item >= B * NCH) return;
  const int b = item / NCH, k = item - b * NCH;
  const int l = threadIdx.x & 63;
  const int len = lens[b];
  const int kb = (len >= 2) ? (len - 2) / CH : 0;

  const int* tb = tags + (size_t)b * S_LEN;
  const float* emb = em + (size_t)b * S_LEN * 64;

  float t = 0.f;
  // ---- gold score slice (negated): steps t0 = k*CH+1 .. min((k+1)CH, len-1)
  {
    float sc = 0.f;
    int t0 = k * CH + 1 + l;
    if (t0 <= min((k + 1) * CH, len - 1)) {
      int cur = tb[t0], prev = tb[t0 - 1];
      sc = emb[(size_t)t0 * 64 + cur] + trans[prev * 64 + cur];
    }
    if (k == 0) {
      if (l == 32) sc += trans[BOS_TAG * 64 + tb[0]] + emb[tb[0]];
      if (l == 33) sc += trans[tb[len - 1] * 64 + EOS_TAG];
    }
    t -= wave_sum_all(sc);
  }

  const unsigned short* vf = Vf + ((size_t)b * NCH + k) * 64;
  if (k == 0) {
    float v0 = bf2f(vf[l]);
    if (kb == 0) {
      t += m0a[b] + LN2F * sf[b * NCH] + __logf(wave_sum_all(v0 * tvf[l]));
    } else {
      t += m0a[b] + LN2F * (sf[b * NCH] + sb[b * NCH + 1])
         + __logf(wave_sum_all(v0 * bf2f(Vb[((size_t)b * NCH + 1) * 64 + l])));
    }
  } else if (k < kb) {
    float vk = bf2f(vf[l]);
    t += LN2F * sb[b * NCH + k + 1]
       + __logf(wave_sum_all(vk * bf2f(Vb[((size_t)b * NCH + k + 1) * 64 + l])))
       - __logf(wave_sum_all(vk));
  } else if (k == kb) {
    float vk = bf2f(vf[l]);
    t += __logf(wave_sum_all(vk * tvf[l])) - __logf(wave_sum_all(vk));
  }

  if (l == 0) term[item] = t;
}

// ===== final: sum all terms -> out[0] =====
__global__ __launch_bounds__(1024) void crf_final(
    const float* __restrict__ term, float* __restrict__ out, int n)
{
  __shared__ float red[16];
  float s = 0.f;
  for (int i = threadIdx.x; i < n; i += 1024) s += term[i];
  s = wave_sum_all(s);
  const int wid = threadIdx.x >> 6;
  if ((threadIdx.x & 63) == 0) red[wid] = s;
  __syncthreads();
  if (threadIdx.x == 0) {
    float tot = 0.f;
#pragma unroll
    for (int i = 0; i < 16; ++i) tot += red[i];
    out[0] = tot;
  }
}

// ===== fallback: monolithic per-batch forward (VALU, linear space) =====
__global__ __launch_bounds__(64) void crf_mono(
    const float* __restrict__ em, const int* __restrict__ tags,
    const float* __restrict__ mask, const float* __restrict__ trans,
    float* __restrict__ partial)
{
  const int b = blockIdx.x;
  const int l = threadIdx.x;
  const float* emb = em + (size_t)b * S_LEN * 64;
  const float* mb = mask + (size_t)b * S_LEN;
  float lenf = 0.f;
  for (int t = l; t < S_LEN; t += 64) lenf += mb[t];
  lenf = wave_sum_all(lenf);
  const int len = max(1, min(S_LEN, (int)(lenf + 0.5f)));

  float p[64];
#pragma unroll
  for (int i = 0; i < 64; ++i) p[i] = __expf(trans[i * 64 + l]) * 0.015625f;

  const int* tb = tags + (size_t)b * S_LEN;
  float sc = 0.f;
  for (int tt = 1 + l; tt <= len - 1; tt += 64)
    sc += emb[(size_t)tt * 64 + tb[tt]] + trans[tb[tt - 1] * 64 + tb[tt]];
  sc = wave_sum_all(sc);
  sc += trans[BOS_TAG * 64 + tb[0]] + emb[tb[0]] + trans[tb[len - 1] * 64 + EOS_TAG];

  float a0 = trans[BOS_TAG * 64 + l] + emb[l];
  float m0 = wave_fmax_all(a0);
  float v = __expf(a0 - m0);
  int sigma = 0;
  for (int t = 1; t <= len - 1; ++t) {
    float E = __expf(emb[(size_t)t * 64 + l]);
    int xi = __float_as_int(v);
    float s0 = 0.f, s1 = 0.f, s2 = 0.f, s3 = 0.f;
#pragma unroll
    for (int i = 0; i < 64; i += 4) {
      s0 = fmaf(__int_as_float(__builtin_amdgcn_readlane(xi, i + 0)), p[i + 0], s0);
      s1 = fmaf(__int_as_float(__builtin_amdgcn_readlane(xi, i + 1)), p[i + 1], s1);
      s2 = fmaf(__int_as_float(__builtin_amdgcn_readlane(xi, i + 2)), p[i + 2], s2);
      s3 = fmaf(__int_as_float(__builtin_amdgcn_readlane(xi, i + 3)), p[i + 3], s3);
    }
    v = ((s0 + s1) + (s2 + s3)) * E;
    float m = wave_fmax_all(v);
    int e = ((__float_as_int(m) >> 23) & 0xff) - 127;
    sigma += e + 6;
    v *= __int_as_float((127 - e) << 23);
  }
  float tvec = __expf(trans[l * 64 + EOS_TAG]);
  float lp = m0 + LN2F * (float)sigma + __logf(wave_sum_all(v * tvec));
  if (l == 0) partial[b] = lp - sc;
}

extern "C" void kernel_launch(void* const* d_in, const int* in_sizes, int n_in,
                              void* d_out, int out_size, void* d_ws, size_t ws_size,
                              hipStream_t stream) {
  const float* em = (const float*)d_in[0];
  const int* tags = (const int*)d_in[1];
  const float* mask = (const float*)d_in[2];
  const float* trans = (const float*)d_in[3];
  float* out = (float*)d_out;

  const int B = in_sizes[1] / S_LEN;

  const size_t nSig = (size_t)B * NCH;
  const size_t nV   = (size_t)B * NCH * 64;
  const size_t need = 16384 + 64 * sizeof(float)
                    + (3 * nSig + (size_t)B) * sizeof(float)
                    + (size_t)B * sizeof(int)
                    + 2 * nV * sizeof(unsigned short);

  if (ws_size >= need) {
    short8* pfrag = (short8*)d_ws;
    float* tvf  = (float*)((char*)d_ws + 16384);
    float* sf   = tvf + 64;
    float* sb   = sf + nSig;
    float* m0a  = sb + nSig;
    float* term = m0a + B;
    int*   lens = (int*)(term + nSig);
    unsigned short* Vf = (unsigned short*)(lens + B);
    unsigned short* Vb = Vf + nV;

    crf_prep<<<(B + 3) / 4, 256, 0, stream>>>(mask, trans, lens, pfrag, tvf, B);
    const int nwaves = 2 * B * WPB;
    crf_chunk_mfma<<<(nwaves + 3) / 4, 256, 0, stream>>>(
        em, trans, lens, pfrag, Vf, Vb, sf, sb, m0a, B);
    crf_combine<<<(B * NCH + 3) / 4, 256, 0, stream>>>(
        em, tags, trans, lens, Vf, Vb, sf, sb, m0a, tvf, term, B);
    crf_final<<<1, 1024, 0, stream>>>(term, out, B * NCH);
  } else {
    float* partial = (float*)d_ws;
    crf_mono<<<B, 64, 0, stream>>>(em, tags, mask, trans, partial);
    crf_final<<<1, 1024, 0, stream>>>(partial, out, B);
  }
}